// Round 23
// baseline (49.152 us; speedup 1.0000x reference)
//
#include <hip/hip_runtime.h>

// ChamferLoss via DUAL-PASS 32x32x16 MFMA (R20 structure, XCD-swizzled — best
// measured: 35.4us). R23: revert R22's REG_A=4 (null); fuse the final reduce
// into cf_mf7 via sync-free last-block reduction (atomicExch partial writes,
// device counter, last block reduces 1024 partials in FIXED tid order ->
// bit-deterministic). Removes 1 dispatch + 1 launch gap. grid.sync banned (R21).

#define NPTS 2048
#define NB 64
#define BLK 256

#define PREDS_A 49152
#define PREDS_C 16384
#define GTS_A 6144
#define GTS_C 2048

// ---- ws layout ----
#define OFF_PART  0                        // float partial[1024] = 4 KB
#define OFF_CNT   4096                     // unsigned counter
#define OFF_XPK   8192                     // ushort xpkB: 4 MB
#define OFF_YPK   4202496                  // ushort ypkB: 4 MB
#define WS_REQ    8396800

using bf16x8  = __attribute__((ext_vector_type(8))) __bf16;
using short8v = __attribute__((ext_vector_type(8))) short;
using f32x16  = __attribute__((ext_vector_type(16))) float;

static __device__ __forceinline__ unsigned short f2bf(float f) {
    unsigned u = __float_as_uint(f);
    u = u + 0x7FFFu + ((u >> 16) & 1u);      // RNE
    return (unsigned short)(u >> 16);
}
static __device__ __forceinline__ float bf2f(unsigned short h) {
    return __uint_as_float(((unsigned)h) << 16);
}
static __device__ __forceinline__ float min3f(float a, float b, float c) {
    return fminf(fminf(a, b), c);            // clang fuses to v_min3_f32
}

// verified R15/R16 in-register A-fragment (a = -2*query)
static __device__ __forceinline__ bf16x8 makeA(float x0, float x1, float x2, int lh) {
    const float rx = fmaf(x0, x0, fmaf(x1, x1, x2 * x2));
    const float a0 = -2.f * x0, a1 = -2.f * x1, a2 = -2.f * x2;
    const unsigned short h0 = f2bf(a0), h1 = f2bf(a1), h2 = f2bf(a2);
    const unsigned short lo0 = f2bf(a0 - bf2f(h0));
    const unsigned short lo1 = f2bf(a1 - bf2f(h1));
    const unsigned short lo2 = f2bf(a2 - bf2f(h2));
    const unsigned short rh = f2bf(rx), rl = f2bf(rx - bf2f(rh));
    const unsigned short one = 0x3F80;
    short8v av;
    av[0] = (short)(lh ? lo2 : h0);
    av[1] = (short)(lh ? rh  : h1);
    av[2] = (short)(lh ? rl  : h2);
    av[3] = (short)(lh ? one : h0);
    av[4] = (short)(lh ? one : h1);
    av[5] = (short)(lh ? (unsigned short)0 : h2);
    av[6] = (short)(lh ? (unsigned short)0 : lo0);
    av[7] = (short)(lh ? (unsigned short)0 : lo1);
    return __builtin_bit_cast(bf16x8, av);
}

// pack one point into B-layout (verified R16)
static __device__ __forceinline__ void packB(float v0, float v1, float v2,
                                             unsigned short* dst) {
    const unsigned short one = 0x3F80;
    const float rr = fmaf(v0, v0, fmaf(v1, v1, v2 * v2));
    const unsigned short h0 = f2bf(v0), h1 = f2bf(v1), h2 = f2bf(v2);
    const unsigned short l0 = f2bf(v0 - bf2f(h0));
    const unsigned short l1 = f2bf(v1 - bf2f(h1));
    const unsigned short l2 = f2bf(v2 - bf2f(h2));
    const unsigned short rh = f2bf(rr), rl = f2bf(rr - bf2f(rh));
    alignas(16) unsigned short t[16] =
        {h0, h1, h2, l0, l1, l2, h0, h1, h2, one, one, rh, rl, 0, 0, 0};
    uint4* d4 = (uint4*)dst;
    d4[0] = *(const uint4*)&t[0];
    d4[1] = *(const uint4*)&t[8];
}

// ---------- prep: pack BOTH sides + zero the done-counter ----------
__global__ __launch_bounds__(256) void cf_prep4(
    const float* __restrict__ preds, const float* __restrict__ gts,
    const int* __restrict__ idx,
    unsigned short* __restrict__ xpkB, unsigned short* __restrict__ ypkB,
    unsigned* __restrict__ counter)
{
    const int blk = blockIdx.x, tid = threadIdx.x;
    if (blk == 0 && tid == 0) *counter = 0;
    const int p = (blk & 511) * 256 + tid;   // 0..131071
    const int b = p >> 11, j = p & 2047;
    const int i0 = idx[2 * b];
    if (blk < 512) {
        const int m1 = idx[2 * b + 1];
        const float* pb = preds + i0 * PREDS_A + m1 + j * 8;
        packB(pb[0], pb[PREDS_C], pb[2 * PREDS_C], xpkB + (size_t)p * 16);
    } else {
        const float* gb = gts + i0 * GTS_A + j;
        packB(gb[0], gb[GTS_C], gb[2 * GTS_C], ypkB + (size_t)p * 16);
    }
}

// ---------- main: grid 1024, XCD-swizzled (R20-verified) + fused final reduce ----
__global__ __launch_bounds__(BLK, 4) void cf_mf9(
    const float* __restrict__ preds, const float* __restrict__ gts,
    const int* __restrict__ idx,
    const unsigned short* __restrict__ xpkB, const unsigned short* __restrict__ ypkB,
    float* __restrict__ partial, unsigned* __restrict__ counter,
    float* __restrict__ out)
{
    const int tid = threadIdx.x;
    const int bid = blockIdx.x;
    const int xcdslot = bid & 7;
    const int bsub = (bid >> 3) & 7;
    const int b = xcdslot * 8 + bsub;
    const int rest = bid >> 6;               // 0..15
    const int pass = rest >> 3;
    const int strip = rest & 7;

    __shared__ float smw[4];
    __shared__ int islast;

    const int l = tid & 63, w = tid >> 6;
    const int lc = l & 31, lh = l >> 5;

    // ---- two in-register A-fragments ----
    const int i0 = idx[2 * b];
    const int row0 = strip * 256 + w * 64 + lc;
    float x0a, x1a, x2a, x0b, x1b, x2b;
    if (pass == 0) {
        const int m1 = idx[2 * b + 1];
        const float* pb = preds + i0 * PREDS_A + m1 + row0 * 8;
        x0a = pb[0];   x1a = pb[PREDS_C];       x2a = pb[2 * PREDS_C];
        x0b = pb[256]; x1b = pb[PREDS_C + 256]; x2b = pb[2 * PREDS_C + 256];
    } else {
        const float* gb = gts + i0 * GTS_A + row0;
        x0a = gb[0];  x1a = gb[GTS_C];      x2a = gb[2 * GTS_C];
        x0b = gb[32]; x1b = gb[GTS_C + 32]; x2b = gb[2 * GTS_C + 32];
    }
    const bf16x8 af0 = makeA(x0a, x1a, x2a, lh);
    const bf16x8 af1 = makeA(x0b, x1b, x2b, lh);

    float rmA[16], rmB[16];
#pragma unroll
    for (int r = 0; r < 16; ++r) { rmA[r] = INFINITY; rmB[r] = INFINITY; }

    const f32x16 z = {0.f, 0.f, 0.f, 0.f, 0.f, 0.f, 0.f, 0.f,
                      0.f, 0.f, 0.f, 0.f, 0.f, 0.f, 0.f, 0.f};

    const unsigned short* refpk = pass ? xpkB : ypkB;
    const short8v* yp = (const short8v*)refpk + (b * NPTS * 2 + lc * 2 + lh);

    // reg double-buffer (R13-proven)
    bf16x8 curA = __builtin_bit_cast(bf16x8, yp[0]);
    bf16x8 curB = __builtin_bit_cast(bf16x8, yp[64]);

#pragma unroll 2
    for (int s = 0; s < 32; ++s) {
        const int nidx = (s < 31) ? (2 * s + 2) * 64 : 0;
        const bf16x8 nxtA = __builtin_bit_cast(bf16x8, yp[nidx]);
        const bf16x8 nxtB = __builtin_bit_cast(bf16x8, yp[nidx + 64]);

        __builtin_amdgcn_s_setprio(1);
        f32x16 acc0A = __builtin_amdgcn_mfma_f32_32x32x16_bf16(af0, curA, z, 0, 0, 0);
        f32x16 acc0B = __builtin_amdgcn_mfma_f32_32x32x16_bf16(af0, curB, z, 0, 0, 0);
        __builtin_amdgcn_s_setprio(0);
#pragma unroll
        for (int r = 0; r < 16; ++r) rmA[r] = min3f(acc0A[r], acc0B[r], rmA[r]);

        __builtin_amdgcn_s_setprio(1);
        f32x16 acc1A = __builtin_amdgcn_mfma_f32_32x32x16_bf16(af1, curA, z, 0, 0, 0);
        f32x16 acc1B = __builtin_amdgcn_mfma_f32_32x32x16_bf16(af1, curB, z, 0, 0, 0);
        __builtin_amdgcn_s_setprio(0);
#pragma unroll
        for (int r = 0; r < 16; ++r) rmB[r] = min3f(acc1A[r], acc1B[r], rmB[r]);

        curA = nxtA; curB = nxtB;
    }

    // ---- finalize: butterfly col-min, clamp, per-lane row-sum ----
    float lsum = 0.f;
#pragma unroll
    for (int r = 0; r < 16; ++r) {
        float va = rmA[r], vb = rmB[r];
        va = fminf(va, __shfl_xor(va, 1, 32));
        va = fminf(va, __shfl_xor(va, 2, 32));
        va = fminf(va, __shfl_xor(va, 4, 32));
        va = fminf(va, __shfl_xor(va, 8, 32));
        va = fminf(va, __shfl_xor(va, 16, 32));
        vb = fminf(vb, __shfl_xor(vb, 1, 32));
        vb = fminf(vb, __shfl_xor(vb, 2, 32));
        vb = fminf(vb, __shfl_xor(vb, 4, 32));
        vb = fminf(vb, __shfl_xor(vb, 8, 32));
        vb = fminf(vb, __shfl_xor(vb, 16, 32));
        lsum += fmaxf(va, 0.f) + fmaxf(vb, 0.f);
    }
    lsum = (lc == 0) ? lsum : 0.f;
    lsum += __shfl_xor(lsum, 32, 64);          // merge lh halves
    if (l == 0) smw[w] = lsum;
    __syncthreads();

    // ---- publish partial (coherent-point write) + last-block detection ----
    if (tid == 0) {
        const float p = smw[0] + smw[1] + smw[2] + smw[3];
        atomicExch(&partial[bid], p);          // device-coherent write
        __threadfence();
        const unsigned t = atomicAdd(counter, 1u);
        islast = (t == 1023u) ? 1 : 0;
    }
    __syncthreads();

    // ---- last block reduces all 1024 partials in FIXED tid order ----
    if (islast) {
        float s = 0.f;
#pragma unroll
        for (int i = 0; i < 4; ++i)
            s += atomicAdd(&partial[tid + i * 256], 0.0f);   // coherent read
#pragma unroll
        for (int off = 32; off > 0; off >>= 1)
            s += __shfl_down(s, off, 64);
        if ((tid & 63) == 0) smw[tid >> 6] = s;
        __syncthreads();
        if (tid == 0)
            out[0] = (smw[0] + smw[1] + smw[2] + smw[3]) * (1.0f / 64.0f);
    }
}

// ================= fallback (proven R6 path) if ws too small =================
#define NMIN (2 * NB * NPTS)
#define FIT 128
#define FJT 128
#define PADI(j) ((j) + ((j) >> 4))

__global__ __launch_bounds__(256) void cf_init(unsigned* __restrict__ colbuf) {
    int i = blockIdx.x * 256 + threadIdx.x;
    colbuf[i] = 0x7F800000u;
}

__global__ __launch_bounds__(BLK, 4) void cf_tile_lds(
    const float* __restrict__ preds, const float* __restrict__ gts,
    const int* __restrict__ idx, unsigned* __restrict__ minbuf)
{
    const int tid = threadIdx.x;
    const int bid = blockIdx.x;
    const int it = bid & 15;
    const int b = bid >> 4;
    const int i0 = idx[2 * b];
    const int m1 = idx[2 * b + 1];
    const float* pbase = preds + i0 * PREDS_A + m1;
    const float* gbase = gts + i0 * GTS_A;

    __shared__ float4 sq[PADI(FIT - 1) + 2];
    __shared__ float4 sr[PADI(NPTS - 1) + 2];
    __shared__ float  scolw[4][FJT];

    if (tid < FIT) {
        const int i = it * FIT + tid;
        const float q0 = pbase[i * 8];
        const float q1 = pbase[i * 8 + PREDS_C];
        const float q2 = pbase[i * 8 + 2 * PREDS_C];
        const float rq = fmaf(q0, q0, fmaf(q1, q1, q2 * q2));
        sq[PADI(tid)] = make_float4(-2.f * q0, -2.f * q1, -2.f * q2, rq);
    }
#pragma unroll
    for (int k = 0; k < 8; ++k) {
        const int j = tid + BLK * k;
        const float r0 = gbase[j];
        const float r1 = gbase[j + GTS_C];
        const float r2 = gbase[j + 2 * GTS_C];
        const float rr = fmaf(r0, r0, fmaf(r1, r1, r2 * r2));
        sr[PADI(j)] = make_float4(r0, r1, r2, rr);
    }
    __syncthreads();

    const int ty = tid >> 4, tx = tid & 15;
    float nq0[8], nq1[8], nq2[8], rq[8], rmin[8];
#pragma unroll
    for (int u = 0; u < 8; ++u) {
        const float4 q = sq[PADI(ty * 8 + u)];
        nq0[u] = q.x; nq1[u] = q.y; nq2[u] = q.z; rq[u] = q.w;
        rmin[u] = INFINITY;
    }
    unsigned* rowbuf = minbuf;
    unsigned* colbuf = minbuf + NB * NPTS;

    for (int jt = 0; jt < NPTS / FJT; ++jt) {
        float4 r[8];
        const int rb = PADI(jt * FJT + tx * 8);
#pragma unroll
        for (int v = 0; v < 8; ++v) r[v] = sr[rb + v];
        float cmin[8];
#pragma unroll
        for (int v = 0; v < 8; ++v) cmin[v] = INFINITY;
#pragma unroll
        for (int v = 0; v < 8; v += 2) {
#pragma unroll
            for (int u = 0; u < 8; u += 2) {
                float s00 = fmaf(nq2[u], r[v].z, r[v].w);
                s00 = fmaf(nq1[u], r[v].y, s00);
                s00 = fmaf(nq0[u], r[v].x, s00);
                float s01 = fmaf(nq2[u], r[v + 1].z, r[v + 1].w);
                s01 = fmaf(nq1[u], r[v + 1].y, s01);
                s01 = fmaf(nq0[u], r[v + 1].x, s01);
                float s10 = fmaf(nq2[u + 1], r[v].z, r[v].w);
                s10 = fmaf(nq1[u + 1], r[v].y, s10);
                s10 = fmaf(nq0[u + 1], r[v].x, s10);
                float s11 = fmaf(nq2[u + 1], r[v + 1].z, r[v + 1].w);
                s11 = fmaf(nq1[u + 1], r[v + 1].y, s11);
                s11 = fmaf(nq0[u + 1], r[v + 1].x, s11);
                rmin[u]     = min3f(s00, s01, rmin[u]);
                rmin[u + 1] = min3f(s10, s11, rmin[u + 1]);
                const float d00 = s00 + rq[u];
                const float d10 = s10 + rq[u + 1];
                const float d01 = s01 + rq[u];
                const float d11 = s11 + rq[u + 1];
                cmin[v]     = min3f(d00, d10, cmin[v]);
                cmin[v + 1] = min3f(d01, d11, cmin[v + 1]);
            }
        }
#pragma unroll
        for (int v = 0; v < 8; ++v) {
            float c = cmin[v];
            c = fminf(c, __shfl_xor(c, 16, 64));
            c = fminf(c, __shfl_xor(c, 32, 64));
            cmin[v] = c;
        }
        if (((tid >> 4) & 3) == 0) {
            const int w = tid >> 6;
            *(float4*)&scolw[w][tx * 8]     = make_float4(cmin[0], cmin[1], cmin[2], cmin[3]);
            *(float4*)&scolw[w][tx * 8 + 4] = make_float4(cmin[4], cmin[5], cmin[6], cmin[7]);
        }
        __syncthreads();
        if (tid < FJT) {
            float m = fminf(min3f(scolw[0][tid], scolw[1][tid], scolw[2][tid]), scolw[3][tid]);
            m = fmaxf(m, 0.0f);
            atomicMin(&colbuf[b * NPTS + jt * FJT + tid], __float_as_uint(m));
        }
        __syncthreads();
    }
#pragma unroll
    for (int u = 0; u < 8; ++u) {
        float rm = rmin[u];
        rm = fminf(rm, __shfl_xor(rm, 1, 16));
        rm = fminf(rm, __shfl_xor(rm, 2, 16));
        rm = fminf(rm, __shfl_xor(rm, 4, 16));
        rm = fminf(rm, __shfl_xor(rm, 8, 16));
        rmin[u] = rm;
    }
    if (tx == 0) {
#pragma unroll
        for (int u = 0; u < 8; ++u) {
            const float d = fmaxf(rmin[u] + rq[u], 0.0f);
            rowbuf[b * NPTS + it * FIT + ty * 8 + u] = __float_as_uint(d);
        }
    }
}

__global__ __launch_bounds__(256) void cf_reduce1(const unsigned* __restrict__ minbuf,
                                                  float* __restrict__ partial) {
    __shared__ float sm[4];
    const int base = blockIdx.x * 1024;
    float s = 0.0f;
    for (int k = threadIdx.x; k < 1024; k += 256)
        s += __uint_as_float(minbuf[base + k]);
#pragma unroll
    for (int off = 32; off > 0; off >>= 1)
        s += __shfl_down(s, off, 64);
    if ((threadIdx.x & 63) == 0) sm[threadIdx.x >> 6] = s;
    __syncthreads();
    if (threadIdx.x == 0)
        partial[blockIdx.x] = sm[0] + sm[1] + sm[2] + sm[3];
}

__global__ __launch_bounds__(256) void cf_reduce2(const float* __restrict__ partial,
                                                  float* __restrict__ out) {
    __shared__ float sm[4];
    float s = (threadIdx.x < 128) ? partial[threadIdx.x] : 0.f;
#pragma unroll
    for (int off = 32; off > 0; off >>= 1)
        s += __shfl_down(s, off, 64);
    if ((threadIdx.x & 63) == 0) sm[threadIdx.x >> 6] = s;
    __syncthreads();
    if (threadIdx.x == 0)
        out[0] = (sm[0] + sm[1] + sm[2] + sm[3]) * (1.0f / 64.0f);
}

extern "C" void kernel_launch(void* const* d_in, const int* in_sizes, int n_in,
                              void* d_out, int out_size, void* d_ws, size_t ws_size,
                              hipStream_t stream) {
    const float* preds = (const float*)d_in[0];
    const float* gts   = (const float*)d_in[1];
    const int*   idx   = (const int*)d_in[2];
    float* out = (float*)d_out;

    if (ws_size >= (size_t)WS_REQ) {
        float* partial   = (float*)((char*)d_ws + OFF_PART);
        unsigned* counter = (unsigned*)((char*)d_ws + OFF_CNT);
        unsigned short* xpkB = (unsigned short*)((char*)d_ws + OFF_XPK);
        unsigned short* ypkB = (unsigned short*)((char*)d_ws + OFF_YPK);
        cf_prep4<<<1024, 256, 0, stream>>>(preds, gts, idx, xpkB, ypkB, counter);
        cf_mf9<<<1024, BLK, 0, stream>>>(preds, gts, idx, xpkB, ypkB,
                                         partial, counter, out);
    } else {
        unsigned* minbuf = (unsigned*)d_ws;
        unsigned* colbuf = minbuf + NB * NPTS;
        float* partial   = (float*)((char*)d_ws + NMIN * 4);
        cf_init<<<(NB * NPTS) / 256, 256, 0, stream>>>(colbuf);
        cf_tile_lds<<<NB * (NPTS / FIT), BLK, 0, stream>>>(preds, gts, idx, minbuf);
        cf_reduce1<<<NMIN / 1024, 256, 0, stream>>>(minbuf, partial);
        cf_reduce2<<<1, 256, 0, stream>>>(partial, out);
    }
}

// Round 24
// 35.177 us; speedup vs baseline: 1.3973x; 1.3973x over previous
//
#include <hip/hip_runtime.h>

// ChamferLoss via DUAL-PASS 32x32x16 MFMA — R20 configuration (proven best,
// 35.4us). R24 = confirmation revert after R23's last-block fusion regressed
// (+25us: single-counter cross-XCD atomics + per-block threadfence).
// Structure: prep3 (pack both sides, B-layout) -> cf_mf7 (XCD-swizzled,
// REG_A=2, reg-double-buffered, register-resident row-mins) -> red2b.

#define NPTS 2048
#define NB 64
#define BLK 256

#define PREDS_A 49152
#define PREDS_C 16384
#define GTS_A 6144
#define GTS_C 2048

// ---- ws layout ----
#define OFF_PART  0                        // float partial[1024] = 4 KB
#define OFF_XPK   4096                     // ushort xpkB: 4 MB (B-layout of x)
#define OFF_YPK   4198400                  // ushort ypkB: 4 MB (B-layout of y)
#define WS_REQ    8392704

using bf16x8  = __attribute__((ext_vector_type(8))) __bf16;
using short8v = __attribute__((ext_vector_type(8))) short;
using f32x16  = __attribute__((ext_vector_type(16))) float;

static __device__ __forceinline__ unsigned short f2bf(float f) {
    unsigned u = __float_as_uint(f);
    u = u + 0x7FFFu + ((u >> 16) & 1u);      // RNE
    return (unsigned short)(u >> 16);
}
static __device__ __forceinline__ float bf2f(unsigned short h) {
    return __uint_as_float(((unsigned)h) << 16);
}
static __device__ __forceinline__ float min3f(float a, float b, float c) {
    return fminf(fminf(a, b), c);            // clang fuses to v_min3_f32
}

// verified R15/R16 in-register A-fragment (a = -2*query)
static __device__ __forceinline__ bf16x8 makeA(float x0, float x1, float x2, int lh) {
    const float rx = fmaf(x0, x0, fmaf(x1, x1, x2 * x2));
    const float a0 = -2.f * x0, a1 = -2.f * x1, a2 = -2.f * x2;
    const unsigned short h0 = f2bf(a0), h1 = f2bf(a1), h2 = f2bf(a2);
    const unsigned short lo0 = f2bf(a0 - bf2f(h0));
    const unsigned short lo1 = f2bf(a1 - bf2f(h1));
    const unsigned short lo2 = f2bf(a2 - bf2f(h2));
    const unsigned short rh = f2bf(rx), rl = f2bf(rx - bf2f(rh));
    const unsigned short one = 0x3F80;
    short8v av;
    av[0] = (short)(lh ? lo2 : h0);
    av[1] = (short)(lh ? rh  : h1);
    av[2] = (short)(lh ? rl  : h2);
    av[3] = (short)(lh ? one : h0);
    av[4] = (short)(lh ? one : h1);
    av[5] = (short)(lh ? (unsigned short)0 : h2);
    av[6] = (short)(lh ? (unsigned short)0 : lo0);
    av[7] = (short)(lh ? (unsigned short)0 : lo1);
    return __builtin_bit_cast(bf16x8, av);
}

// pack one point into B-layout (verified R16)
static __device__ __forceinline__ void packB(float v0, float v1, float v2,
                                             unsigned short* dst) {
    const unsigned short one = 0x3F80;
    const float rr = fmaf(v0, v0, fmaf(v1, v1, v2 * v2));
    const unsigned short h0 = f2bf(v0), h1 = f2bf(v1), h2 = f2bf(v2);
    const unsigned short l0 = f2bf(v0 - bf2f(h0));
    const unsigned short l1 = f2bf(v1 - bf2f(h1));
    const unsigned short l2 = f2bf(v2 - bf2f(h2));
    const unsigned short rh = f2bf(rr), rl = f2bf(rr - bf2f(rh));
    alignas(16) unsigned short t[16] =
        {h0, h1, h2, l0, l1, l2, h0, h1, h2, one, one, rh, rl, 0, 0, 0};
    uint4* d4 = (uint4*)dst;
    d4[0] = *(const uint4*)&t[0];
    d4[1] = *(const uint4*)&t[8];
}

// ---------- prep: pack BOTH sides in B-layout (1024 blocks) ----------
__global__ __launch_bounds__(256) void cf_prep3(
    const float* __restrict__ preds, const float* __restrict__ gts,
    const int* __restrict__ idx,
    unsigned short* __restrict__ xpkB, unsigned short* __restrict__ ypkB)
{
    const int blk = blockIdx.x, tid = threadIdx.x;
    const int p = (blk & 511) * 256 + tid;   // 0..131071
    const int b = p >> 11, j = p & 2047;
    const int i0 = idx[2 * b];
    if (blk < 512) {
        const int m1 = idx[2 * b + 1];
        const float* pb = preds + i0 * PREDS_A + m1 + j * 8;
        packB(pb[0], pb[PREDS_C], pb[2 * PREDS_C], xpkB + (size_t)p * 16);
    } else {
        const float* gb = gts + i0 * GTS_A + j;
        packB(gb[0], gb[GTS_C], gb[2 * GTS_C], ypkB + (size_t)p * 16);
    }
}

// ---------- main: grid 1024, XCD-swizzled decode (R20-verified) ----------
// bid bits: [rest:4][bsub:3][xcdslot:3]; b = xcdslot*8 + bsub; rest = pass*8+strip.
// All 16 blocks of batch b share bid%8 -> same XCD -> batch slab L2-resident.
__global__ __launch_bounds__(BLK, 4) void cf_mf7(
    const float* __restrict__ preds, const float* __restrict__ gts,
    const int* __restrict__ idx,
    const unsigned short* __restrict__ xpkB, const unsigned short* __restrict__ ypkB,
    float* __restrict__ partial)
{
    const int tid = threadIdx.x;
    const int bid = blockIdx.x;
    const int xcdslot = bid & 7;
    const int bsub = (bid >> 3) & 7;
    const int b = xcdslot * 8 + bsub;
    const int rest = bid >> 6;               // 0..15
    const int pass = rest >> 3;
    const int strip = rest & 7;

    __shared__ float smw[4];

    const int l = tid & 63, w = tid >> 6;
    const int lc = l & 31, lh = l >> 5;

    // ---- two in-register A-fragments ----
    const int i0 = idx[2 * b];
    const int row0 = strip * 256 + w * 64 + lc;
    float x0a, x1a, x2a, x0b, x1b, x2b;
    if (pass == 0) {
        const int m1 = idx[2 * b + 1];
        const float* pb = preds + i0 * PREDS_A + m1 + row0 * 8;
        x0a = pb[0];   x1a = pb[PREDS_C];       x2a = pb[2 * PREDS_C];
        x0b = pb[256]; x1b = pb[PREDS_C + 256]; x2b = pb[2 * PREDS_C + 256];
    } else {
        const float* gb = gts + i0 * GTS_A + row0;
        x0a = gb[0];  x1a = gb[GTS_C];      x2a = gb[2 * GTS_C];
        x0b = gb[32]; x1b = gb[GTS_C + 32]; x2b = gb[2 * GTS_C + 32];
    }
    const bf16x8 af0 = makeA(x0a, x1a, x2a, lh);
    const bf16x8 af1 = makeA(x0b, x1b, x2b, lh);

    float rmA[16], rmB[16];
#pragma unroll
    for (int r = 0; r < 16; ++r) { rmA[r] = INFINITY; rmB[r] = INFINITY; }

    const f32x16 z = {0.f, 0.f, 0.f, 0.f, 0.f, 0.f, 0.f, 0.f,
                      0.f, 0.f, 0.f, 0.f, 0.f, 0.f, 0.f, 0.f};

    const unsigned short* refpk = pass ? xpkB : ypkB;
    const short8v* yp = (const short8v*)refpk + (b * NPTS * 2 + lc * 2 + lh);

    // reg double-buffer (R13-proven)
    bf16x8 curA = __builtin_bit_cast(bf16x8, yp[0]);
    bf16x8 curB = __builtin_bit_cast(bf16x8, yp[64]);

#pragma unroll 2
    for (int s = 0; s < 32; ++s) {
        const int nidx = (s < 31) ? (2 * s + 2) * 64 : 0;
        const bf16x8 nxtA = __builtin_bit_cast(bf16x8, yp[nidx]);
        const bf16x8 nxtB = __builtin_bit_cast(bf16x8, yp[nidx + 64]);

        __builtin_amdgcn_s_setprio(1);
        f32x16 acc0A = __builtin_amdgcn_mfma_f32_32x32x16_bf16(af0, curA, z, 0, 0, 0);
        f32x16 acc0B = __builtin_amdgcn_mfma_f32_32x32x16_bf16(af0, curB, z, 0, 0, 0);
        __builtin_amdgcn_s_setprio(0);
#pragma unroll
        for (int r = 0; r < 16; ++r) rmA[r] = min3f(acc0A[r], acc0B[r], rmA[r]);

        __builtin_amdgcn_s_setprio(1);
        f32x16 acc1A = __builtin_amdgcn_mfma_f32_32x32x16_bf16(af1, curA, z, 0, 0, 0);
        f32x16 acc1B = __builtin_amdgcn_mfma_f32_32x32x16_bf16(af1, curB, z, 0, 0, 0);
        __builtin_amdgcn_s_setprio(0);
#pragma unroll
        for (int r = 0; r < 16; ++r) rmB[r] = min3f(acc1A[r], acc1B[r], rmB[r]);

        curA = nxtA; curB = nxtB;
    }

    // ---- finalize: butterfly col-min, clamp, per-lane row-sum ----
    float lsum = 0.f;
#pragma unroll
    for (int r = 0; r < 16; ++r) {
        float va = rmA[r], vb = rmB[r];
        va = fminf(va, __shfl_xor(va, 1, 32));
        va = fminf(va, __shfl_xor(va, 2, 32));
        va = fminf(va, __shfl_xor(va, 4, 32));
        va = fminf(va, __shfl_xor(va, 8, 32));
        va = fminf(va, __shfl_xor(va, 16, 32));
        vb = fminf(vb, __shfl_xor(vb, 1, 32));
        vb = fminf(vb, __shfl_xor(vb, 2, 32));
        vb = fminf(vb, __shfl_xor(vb, 4, 32));
        vb = fminf(vb, __shfl_xor(vb, 8, 32));
        vb = fminf(vb, __shfl_xor(vb, 16, 32));
        lsum += fmaxf(va, 0.f) + fmaxf(vb, 0.f);
    }
    lsum = (lc == 0) ? lsum : 0.f;
    lsum += __shfl_xor(lsum, 32, 64);          // merge lh halves
    if (l == 0) smw[w] = lsum;
    __syncthreads();
    if (tid == 0)
        partial[bid] = smw[0] + smw[1] + smw[2] + smw[3];
}

// ---------- final: sum 1024 partials ----------
__global__ __launch_bounds__(256) void cf_red2b(const float* __restrict__ partial,
                                                float* __restrict__ out) {
    __shared__ float sm[4];
    float s = 0.f;
#pragma unroll
    for (int i = 0; i < 4; ++i) s += partial[threadIdx.x + i * 256];
#pragma unroll
    for (int off = 32; off > 0; off >>= 1)
        s += __shfl_down(s, off, 64);
    if ((threadIdx.x & 63) == 0) sm[threadIdx.x >> 6] = s;
    __syncthreads();
    if (threadIdx.x == 0)
        out[0] = (sm[0] + sm[1] + sm[2] + sm[3]) * (1.0f / 64.0f);
}

// ================= fallback (proven R6 path) if ws too small =================
#define NMIN (2 * NB * NPTS)
#define FIT 128
#define FJT 128
#define PADI(j) ((j) + ((j) >> 4))

__global__ __launch_bounds__(256) void cf_init(unsigned* __restrict__ colbuf) {
    int i = blockIdx.x * 256 + threadIdx.x;
    colbuf[i] = 0x7F800000u;
}

__global__ __launch_bounds__(BLK, 4) void cf_tile_lds(
    const float* __restrict__ preds, const float* __restrict__ gts,
    const int* __restrict__ idx, unsigned* __restrict__ minbuf)
{
    const int tid = threadIdx.x;
    const int bid = blockIdx.x;
    const int it = bid & 15;
    const int b = bid >> 4;
    const int i0 = idx[2 * b];
    const int m1 = idx[2 * b + 1];
    const float* pbase = preds + i0 * PREDS_A + m1;
    const float* gbase = gts + i0 * GTS_A;

    __shared__ float4 sq[PADI(FIT - 1) + 2];
    __shared__ float4 sr[PADI(NPTS - 1) + 2];
    __shared__ float  scolw[4][FJT];

    if (tid < FIT) {
        const int i = it * FIT + tid;
        const float q0 = pbase[i * 8];
        const float q1 = pbase[i * 8 + PREDS_C];
        const float q2 = pbase[i * 8 + 2 * PREDS_C];
        const float rq = fmaf(q0, q0, fmaf(q1, q1, q2 * q2));
        sq[PADI(tid)] = make_float4(-2.f * q0, -2.f * q1, -2.f * q2, rq);
    }
#pragma unroll
    for (int k = 0; k < 8; ++k) {
        const int j = tid + BLK * k;
        const float r0 = gbase[j];
        const float r1 = gbase[j + GTS_C];
        const float r2 = gbase[j + 2 * GTS_C];
        const float rr = fmaf(r0, r0, fmaf(r1, r1, r2 * r2));
        sr[PADI(j)] = make_float4(r0, r1, r2, rr);
    }
    __syncthreads();

    const int ty = tid >> 4, tx = tid & 15;
    float nq0[8], nq1[8], nq2[8], rq[8], rmin[8];
#pragma unroll
    for (int u = 0; u < 8; ++u) {
        const float4 q = sq[PADI(ty * 8 + u)];
        nq0[u] = q.x; nq1[u] = q.y; nq2[u] = q.z; rq[u] = q.w;
        rmin[u] = INFINITY;
    }
    unsigned* rowbuf = minbuf;
    unsigned* colbuf = minbuf + NB * NPTS;

    for (int jt = 0; jt < NPTS / FJT; ++jt) {
        float4 r[8];
        const int rb = PADI(jt * FJT + tx * 8);
#pragma unroll
        for (int v = 0; v < 8; ++v) r[v] = sr[rb + v];
        float cmin[8];
#pragma unroll
        for (int v = 0; v < 8; ++v) cmin[v] = INFINITY;
#pragma unroll
        for (int v = 0; v < 8; v += 2) {
#pragma unroll
            for (int u = 0; u < 8; u += 2) {
                float s00 = fmaf(nq2[u], r[v].z, r[v].w);
                s00 = fmaf(nq1[u], r[v].y, s00);
                s00 = fmaf(nq0[u], r[v].x, s00);
                float s01 = fmaf(nq2[u], r[v + 1].z, r[v + 1].w);
                s01 = fmaf(nq1[u], r[v + 1].y, s01);
                s01 = fmaf(nq0[u], r[v + 1].x, s01);
                float s10 = fmaf(nq2[u + 1], r[v].z, r[v].w);
                s10 = fmaf(nq1[u + 1], r[v].y, s10);
                s10 = fmaf(nq0[u + 1], r[v].x, s10);
                float s11 = fmaf(nq2[u + 1], r[v + 1].z, r[v + 1].w);
                s11 = fmaf(nq1[u + 1], r[v + 1].y, s11);
                s11 = fmaf(nq0[u + 1], r[v + 1].x, s11);
                rmin[u]     = min3f(s00, s01, rmin[u]);
                rmin[u + 1] = min3f(s10, s11, rmin[u + 1]);
                const float d00 = s00 + rq[u];
                const float d10 = s10 + rq[u + 1];
                const float d01 = s01 + rq[u];
                const float d11 = s11 + rq[u + 1];
                cmin[v]     = min3f(d00, d10, cmin[v]);
                cmin[v + 1] = min3f(d01, d11, cmin[v + 1]);
            }
        }
#pragma unroll
        for (int v = 0; v < 8; ++v) {
            float c = cmin[v];
            c = fminf(c, __shfl_xor(c, 16, 64));
            c = fminf(c, __shfl_xor(c, 32, 64));
            cmin[v] = c;
        }
        if (((tid >> 4) & 3) == 0) {
            const int w = tid >> 6;
            *(float4*)&scolw[w][tx * 8]     = make_float4(cmin[0], cmin[1], cmin[2], cmin[3]);
            *(float4*)&scolw[w][tx * 8 + 4] = make_float4(cmin[4], cmin[5], cmin[6], cmin[7]);
        }
        __syncthreads();
        if (tid < FJT) {
            float m = fminf(min3f(scolw[0][tid], scolw[1][tid], scolw[2][tid]), scolw[3][tid]);
            m = fmaxf(m, 0.0f);
            atomicMin(&colbuf[b * NPTS + jt * FJT + tid], __float_as_uint(m));
        }
        __syncthreads();
    }
#pragma unroll
    for (int u = 0; u < 8; ++u) {
        float rm = rmin[u];
        rm = fminf(rm, __shfl_xor(rm, 1, 16));
        rm = fminf(rm, __shfl_xor(rm, 2, 16));
        rm = fminf(rm, __shfl_xor(rm, 4, 16));
        rm = fminf(rm, __shfl_xor(rm, 8, 16));
        rmin[u] = rm;
    }
    if (tx == 0) {
#pragma unroll
        for (int u = 0; u < 8; ++u) {
            const float d = fmaxf(rmin[u] + rq[u], 0.0f);
            rowbuf[b * NPTS + it * FIT + ty * 8 + u] = __float_as_uint(d);
        }
    }
}

__global__ __launch_bounds__(256) void cf_reduce1(const unsigned* __restrict__ minbuf,
                                                  float* __restrict__ partial) {
    __shared__ float sm[4];
    const int base = blockIdx.x * 1024;
    float s = 0.0f;
    for (int k = threadIdx.x; k < 1024; k += 256)
        s += __uint_as_float(minbuf[base + k]);
#pragma unroll
    for (int off = 32; off > 0; off >>= 1)
        s += __shfl_down(s, off, 64);
    if ((threadIdx.x & 63) == 0) sm[threadIdx.x >> 6] = s;
    __syncthreads();
    if (threadIdx.x == 0)
        partial[blockIdx.x] = sm[0] + sm[1] + sm[2] + sm[3];
}

__global__ __launch_bounds__(256) void cf_reduce2(const float* __restrict__ partial,
                                                  float* __restrict__ out) {
    __shared__ float sm[4];
    float s = (threadIdx.x < 128) ? partial[threadIdx.x] : 0.f;
#pragma unroll
    for (int off = 32; off > 0; off >>= 1)
        s += __shfl_down(s, off, 64);
    if ((threadIdx.x & 63) == 0) sm[threadIdx.x >> 6] = s;
    __syncthreads();
    if (threadIdx.x == 0)
        out[0] = (sm[0] + sm[1] + sm[2] + sm[3]) * (1.0f / 64.0f);
}

extern "C" void kernel_launch(void* const* d_in, const int* in_sizes, int n_in,
                              void* d_out, int out_size, void* d_ws, size_t ws_size,
                              hipStream_t stream) {
    const float* preds = (const float*)d_in[0];
    const float* gts   = (const float*)d_in[1];
    const int*   idx   = (const int*)d_in[2];
    float* out = (float*)d_out;

    if (ws_size >= (size_t)WS_REQ) {
        float* partial = (float*)((char*)d_ws + OFF_PART);
        unsigned short* xpkB = (unsigned short*)((char*)d_ws + OFF_XPK);
        unsigned short* ypkB = (unsigned short*)((char*)d_ws + OFF_YPK);
        cf_prep3<<<1024, 256, 0, stream>>>(preds, gts, idx, xpkB, ypkB);
        cf_mf7<<<2 * NB * 8, BLK, 0, stream>>>(preds, gts, idx, xpkB, ypkB, partial);
        cf_red2b<<<1, 256, 0, stream>>>(partial, out);
    } else {
        unsigned* minbuf = (unsigned*)d_ws;
        unsigned* colbuf = minbuf + NB * NPTS;
        float* partial   = (float*)((char*)d_ws + NMIN * 4);
        cf_init<<<(NB * NPTS) / 256, 256, 0, stream>>>(colbuf);
        cf_tile_lds<<<NB * (NPTS / FIT), BLK, 0, stream>>>(preds, gts, idx, minbuf);
        cf_reduce1<<<NMIN / 1024, 256, 0, stream>>>(minbuf, partial);
        cf_reduce2<<<1, 256, 0, stream>>>(partial, out);
    }
}